// Round 1
// baseline (1205.476 us; speedup 1.0000x reference)
//
#include <hip/hip_runtime.h>

// MultiHeadAttention: v(8,1024,512) fp32, pad(8,1,1,1024) int, W1(512,2048), b1(2048),
// W2(8192,512), b2(512) -> out (8,1024,512) fp32 ++ attn (8,16,1024,1024) fp32.
// All matmuls in bf16 MFMA 16x16x32, fp32 accumulate.

typedef __attribute__((ext_vector_type(8))) short bf16x8;
typedef __attribute__((ext_vector_type(4))) float f32x4;
typedef __attribute__((ext_vector_type(4))) unsigned short u16x4;

__device__ __forceinline__ unsigned short f2bf(float f) {
  unsigned u = __builtin_bit_cast(unsigned, f);
  u += 0x7FFFu + ((u >> 16) & 1u);   // RTN-even
  return (unsigned short)(u >> 16);
}

// ---------------- preprocessing ----------------

// fp32 -> bf16 straight cast, 4 elems/thread
__global__ void cvt_bf16_kernel(const float* __restrict__ in,
                                unsigned short* __restrict__ out, int n4) {
  int i = blockIdx.x * blockDim.x + threadIdx.x;
  if (i >= n4) return;
  f32x4 v = reinterpret_cast<const f32x4*>(in)[i];
  u16x4 o;
#pragma unroll
  for (int j = 0; j < 4; ++j) o[j] = f2bf(v[j]);
  reinterpret_cast<u16x4*>(out)[i] = o;
}

// in fp32 [R][C] -> out bf16 [C][R]   (R,C multiples of 32)
__global__ void transpose_cvt_kernel(const float* __restrict__ in,
                                     unsigned short* __restrict__ out,
                                     int R, int C) {
  __shared__ float tile[32][33];
  int c0 = blockIdx.x * 32, r0 = blockIdx.y * 32;
  int tx = threadIdx.x & 31, ty = threadIdx.x >> 5;
#pragma unroll
  for (int i = ty; i < 32; i += 8)
    tile[i][tx] = in[(size_t)(r0 + i) * C + (c0 + tx)];
  __syncthreads();
#pragma unroll
  for (int i = ty; i < 32; i += 8)
    out[(size_t)(c0 + i) * R + (r0 + tx)] = f2bf(tile[tx][i]);
}

// ---------------- GEMM1: kq = v @ W1 + b1 ----------------
// vbf [8192][512] bf16 (A), w1t [2048][512] bf16 (B^T layout), out -> q_ws/k_ws [b*16+h][1024][64]
__launch_bounds__(256)
__global__ void gemm1_kernel(const unsigned short* __restrict__ vbf,
                             const unsigned short* __restrict__ w1t,
                             const float* __restrict__ b1,
                             unsigned short* __restrict__ q_ws,
                             unsigned short* __restrict__ k_ws) {
  const int m0 = blockIdx.y * 128, n0 = blockIdx.x * 128;
  const int w = threadIdx.x >> 6, l = threadIdx.x & 63;
  const int wr = w >> 1, wc = w & 1, lr = l & 15, lg = l >> 4;
  f32x4 acc[4][4];
#pragma unroll
  for (int mi = 0; mi < 4; ++mi)
#pragma unroll
    for (int ni = 0; ni < 4; ++ni) acc[mi][ni] = (f32x4){0.f, 0.f, 0.f, 0.f};

  for (int k0 = 0; k0 < 512; k0 += 32) {
    bf16x8 a[4], bb[4];
#pragma unroll
    for (int mi = 0; mi < 4; ++mi)
      a[mi] = *reinterpret_cast<const bf16x8*>(
          vbf + (size_t)(m0 + wr * 64 + mi * 16 + lr) * 512 + k0 + lg * 8);
#pragma unroll
    for (int ni = 0; ni < 4; ++ni)
      bb[ni] = *reinterpret_cast<const bf16x8*>(
          w1t + (size_t)(n0 + wc * 64 + ni * 16 + lr) * 512 + k0 + lg * 8);
#pragma unroll
    for (int mi = 0; mi < 4; ++mi)
#pragma unroll
      for (int ni = 0; ni < 4; ++ni)
        acc[mi][ni] = __builtin_amdgcn_mfma_f32_16x16x32_bf16(a[mi], bb[ni], acc[mi][ni], 0, 0, 0);
  }
#pragma unroll
  for (int mi = 0; mi < 4; ++mi)
#pragma unroll
    for (int ni = 0; ni < 4; ++ni) {
      int col = n0 + wc * 64 + ni * 16 + lr;
      int h = col >> 7, j = col & 127;
      float bias = b1[col];
#pragma unroll
      for (int r = 0; r < 4; ++r) {
        int row = m0 + wr * 64 + mi * 16 + lg * 4 + r;  // D row = (lane>>4)*4 + reg
        int bb_ = row >> 10, s = row & 1023;
        unsigned short bv = f2bf(acc[mi][ni][r] + bias);
        size_t base = ((size_t)(bb_ * 16 + h) << 16) + (size_t)s * 64;
        if (j < 64) k_ws[base + j] = bv;        // first 64 features = k
        else        q_ws[base + j - 64] = bv;   // last 64 = q
      }
    }
}

// ---------------- fused scores + softmax + attn write + PV ----------------
// grid (32 qtiles, 16 h, 8 b), 512 threads (8 waves). QBLK=32 rows.
__launch_bounds__(512)
__global__ void attn_kernel(const unsigned short* __restrict__ q_ws,
                            const unsigned short* __restrict__ k_ws,
                            const unsigned short* __restrict__ vt,   // bf16 [512][8192] = [c][b*1024+s]
                            const int* __restrict__ pad,             // [8][1024]
                            float* __restrict__ attn_out,            // [8][16][1024][1024]
                            unsigned short* __restrict__ o_ws) {     // bf16 [8][1024][16*512]
  const int qt = blockIdx.x, h = blockIdx.y, b = blockIdx.z;
  const int bh = b * 16 + h;
  const int q0 = qt * 32;
  const int w = threadIdx.x >> 6, l = threadIdx.x & 63;
  const int lr = l & 15, lg = l >> 4;

  __shared__ float red[8][32];
  __shared__ float mrow[32], lrow[32], mnew_s[32];
  __shared__ unsigned short P_lds[32][264];  // stride 264 shorts = 528B: 2-way-max bank conflict

  const unsigned short* qb = q_ws + ((size_t)bh << 16);
  const unsigned short* kb = k_ws + ((size_t)bh << 16);
  const int* pmb = pad + b * 1024;

  // Q fragments held in registers: rows q0..q0+31, d=0..63
  bf16x8 a_q[2][2];
#pragma unroll
  for (int mf = 0; mf < 2; ++mf)
#pragma unroll
    for (int ks = 0; ks < 2; ++ks)
      a_q[mf][ks] = *reinterpret_cast<const bf16x8*>(
          qb + (size_t)(q0 + mf * 16 + lr) * 64 + ks * 32 + lg * 8);

  if (threadIdx.x < 32) { mrow[threadIdx.x] = -1e30f; lrow[threadIdx.x] = 0.f; }
  __syncthreads();

  // per-wave 32-col slice of scores for k-tile kt (KBLK=256, wave w owns cols w*32..)
  auto compute_s = [&](int kt, f32x4 (&s)[2][2]) {
    const int c0 = kt * 256 + w * 32;
#pragma unroll
    for (int mf = 0; mf < 2; ++mf)
#pragma unroll
      for (int nf = 0; nf < 2; ++nf) s[mf][nf] = (f32x4){0.f, 0.f, 0.f, 0.f};
#pragma unroll
    for (int ks = 0; ks < 2; ++ks) {
      bf16x8 bk[2];
#pragma unroll
      for (int nf = 0; nf < 2; ++nf)
        bk[nf] = *reinterpret_cast<const bf16x8*>(
            kb + (size_t)(c0 + nf * 16 + lr) * 64 + ks * 32 + lg * 8);
#pragma unroll
      for (int mf = 0; mf < 2; ++mf)
#pragma unroll
        for (int nf = 0; nf < 2; ++nf)
          s[mf][nf] = __builtin_amdgcn_mfma_f32_16x16x32_bf16(a_q[mf][ks], bk[nf], s[mf][nf], 0, 0, 0);
    }
    int msk0 = pmb[c0 + lr], msk1 = pmb[c0 + 16 + lr];
#pragma unroll
    for (int mf = 0; mf < 2; ++mf)
#pragma unroll
      for (int r = 0; r < 4; ++r) {
        s[mf][0][r] = msk0 ? -1000.f : s[mf][0][r] * 0.125f;
        s[mf][1][r] = msk1 ? -1000.f : s[mf][1][r] * 0.125f;
      }
  };

  // ---- pass A: global row max + sum of exp (online) ----
  for (int kt = 0; kt < 4; ++kt) {
    f32x4 s[2][2];
    compute_s(kt, s);
#pragma unroll
    for (int mf = 0; mf < 2; ++mf)
#pragma unroll
      for (int r = 0; r < 4; ++r) {
        float v = fmaxf(s[mf][0][r], s[mf][1][r]);
#pragma unroll
        for (int off = 1; off < 16; off <<= 1) v = fmaxf(v, __shfl_xor(v, off));
        if (lr == 0) red[w][mf * 16 + lg * 4 + r] = v;
      }
    __syncthreads();
    if (threadIdx.x < 32) {
      float M = red[0][threadIdx.x];
#pragma unroll
      for (int ww = 1; ww < 8; ++ww) M = fmaxf(M, red[ww][threadIdx.x]);
      mnew_s[threadIdx.x] = fmaxf(mrow[threadIdx.x], M);
    }
    __syncthreads();
#pragma unroll
    for (int mf = 0; mf < 2; ++mf)
#pragma unroll
      for (int r = 0; r < 4; ++r) {
        float mn = mnew_s[mf * 16 + lg * 4 + r];
        float v = __expf(s[mf][0][r] - mn) + __expf(s[mf][1][r] - mn);
#pragma unroll
        for (int off = 1; off < 16; off <<= 1) v += __shfl_xor(v, off);
        if (lr == 0) red[w][mf * 16 + lg * 4 + r] = v;
      }
    __syncthreads();
    if (threadIdx.x < 32) {
      float S = 0.f;
#pragma unroll
      for (int ww = 0; ww < 8; ++ww) S += red[ww][threadIdx.x];
      lrow[threadIdx.x] = lrow[threadIdx.x] * __expf(mrow[threadIdx.x] - mnew_s[threadIdx.x]) + S;
      mrow[threadIdx.x] = mnew_s[threadIdx.x];
    }
    __syncthreads();
  }

  float mloc[2][4], linv[2][4];
#pragma unroll
  for (int mf = 0; mf < 2; ++mf)
#pragma unroll
    for (int r = 0; r < 4; ++r) {
      int row = mf * 16 + lg * 4 + r;
      mloc[mf][r] = mrow[row];
      linv[mf][r] = 1.f / lrow[row];
    }

  f32x4 acc_o[2][4];
#pragma unroll
  for (int mf = 0; mf < 2; ++mf)
#pragma unroll
    for (int nfo = 0; nfo < 4; ++nfo) acc_o[mf][nfo] = (f32x4){0.f, 0.f, 0.f, 0.f};

  float* attn_b = attn_out + ((size_t)bh << 20) + (size_t)q0 * 1024;
  const unsigned short* vtb = vt + (size_t)b * 1024;

  // ---- pass B: recompute scores, write attn, PV-accumulate ----
  for (int kt = 0; kt < 4; ++kt) {
    f32x4 s[2][2];
    compute_s(kt, s);
    const int c0 = kt * 256 + w * 32;
#pragma unroll
    for (int mf = 0; mf < 2; ++mf)
#pragma unroll
      for (int nf = 0; nf < 2; ++nf)
#pragma unroll
        for (int r = 0; r < 4; ++r) {
          int row = mf * 16 + lg * 4 + r;
          int col = c0 + nf * 16 + lr;
          float p = __expf(s[mf][nf][r] - mloc[mf][r]) * linv[mf][r];
          attn_b[(size_t)row * 1024 + col] = p;
          P_lds[row][w * 32 + nf * 16 + lr] = f2bf(p);
        }
    __syncthreads();
#pragma unroll
    for (int ks = 0; ks < 8; ++ks) {
      bf16x8 pa[2];
#pragma unroll
      for (int mf = 0; mf < 2; ++mf)
        pa[mf] = *reinterpret_cast<const bf16x8*>(&P_lds[mf * 16 + lr][ks * 32 + lg * 8]);
#pragma unroll
      for (int nfo = 0; nfo < 4; ++nfo) {
        bf16x8 bv = *reinterpret_cast<const bf16x8*>(
            vtb + (size_t)(w * 64 + nfo * 16 + lr) * 8192 + kt * 256 + ks * 32 + lg * 8);
#pragma unroll
        for (int mf = 0; mf < 2; ++mf)
          acc_o[mf][nfo] = __builtin_amdgcn_mfma_f32_16x16x32_bf16(pa[mf], bv, acc_o[mf][nfo], 0, 0, 0);
      }
    }
    __syncthreads();
  }

  // write O tile (bf16) to o_ws [b][s][h*512+c]
#pragma unroll
  for (int mf = 0; mf < 2; ++mf)
#pragma unroll
    for (int nfo = 0; nfo < 4; ++nfo)
#pragma unroll
      for (int r = 0; r < 4; ++r) {
        int row = q0 + mf * 16 + lg * 4 + r;
        int col = w * 64 + nfo * 16 + lr;
        o_ws[(size_t)(b * 1024 + row) * 8192 + h * 512 + col] = f2bf(acc_o[mf][nfo][r]);
      }
}

// ---------------- GEMM2: y = o @ W2 + b2 ----------------
// o_ws [8192][8192] bf16 (A), w2t [512][8192] bf16 (B^T), y [8192][512] fp32
__launch_bounds__(256)
__global__ void gemm2_kernel(const unsigned short* __restrict__ o_ws,
                             const unsigned short* __restrict__ w2t,
                             const float* __restrict__ b2,
                             float* __restrict__ y) {
  const int m0 = blockIdx.y * 64, n0 = blockIdx.x * 128;
  const int w = threadIdx.x >> 6, l = threadIdx.x & 63;
  const int wr = w >> 1, wc = w & 1, lr = l & 15, lg = l >> 4;
  f32x4 acc[2][4];
#pragma unroll
  for (int mi = 0; mi < 2; ++mi)
#pragma unroll
    for (int ni = 0; ni < 4; ++ni) acc[mi][ni] = (f32x4){0.f, 0.f, 0.f, 0.f};

#pragma unroll 2
  for (int k0 = 0; k0 < 8192; k0 += 32) {
    bf16x8 a[2], bb[4];
#pragma unroll
    for (int mi = 0; mi < 2; ++mi)
      a[mi] = *reinterpret_cast<const bf16x8*>(
          o_ws + (size_t)(m0 + wr * 32 + mi * 16 + lr) * 8192 + k0 + lg * 8);
#pragma unroll
    for (int ni = 0; ni < 4; ++ni)
      bb[ni] = *reinterpret_cast<const bf16x8*>(
          w2t + (size_t)(n0 + wc * 64 + ni * 16 + lr) * 8192 + k0 + lg * 8);
#pragma unroll
    for (int mi = 0; mi < 2; ++mi)
#pragma unroll
      for (int ni = 0; ni < 4; ++ni)
        acc[mi][ni] = __builtin_amdgcn_mfma_f32_16x16x32_bf16(a[mi], bb[ni], acc[mi][ni], 0, 0, 0);
  }
#pragma unroll
  for (int mi = 0; mi < 2; ++mi)
#pragma unroll
    for (int ni = 0; ni < 4; ++ni) {
      int col = n0 + wc * 64 + ni * 16 + lr;
      float bias = b2[col];
#pragma unroll
      for (int r = 0; r < 4; ++r)
        y[(size_t)(m0 + wr * 32 + mi * 16 + lg * 4 + r) * 512 + col] = acc[mi][ni][r] + bias;
    }
}

// ---------------- launch ----------------
extern "C" void kernel_launch(void* const* d_in, const int* in_sizes, int n_in,
                              void* d_out, int out_size, void* d_ws, size_t ws_size,
                              hipStream_t stream) {
  const float* v   = (const float*)d_in[0];
  const int*   pad = (const int*)d_in[1];
  const float* W1  = (const float*)d_in[2];
  const float* b1  = (const float*)d_in[3];
  const float* W2  = (const float*)d_in[4];
  const float* b2  = (const float*)d_in[5];
  float* out  = (float*)d_out;
  float* attn = out + (size_t)8 * 1024 * 512;

  char* ws = (char*)d_ws;
  unsigned short* w1t  = (unsigned short*)(ws);              //  2 MB  [2048][512]
  unsigned short* w2t  = (unsigned short*)(ws + 2097152);    //  8 MB  [512][8192]
  unsigned short* vt   = (unsigned short*)(ws + 10485760);   //  8 MB  [512][8192]
  unsigned short* vbf  = (unsigned short*)(ws + 18874368);   //  8 MB  [8192][512]
  unsigned short* q_ws = (unsigned short*)(ws + 27262976);   // 16 MB  [128][1024][64]
  unsigned short* k_ws = (unsigned short*)(ws + 44040192);   // 16 MB  [128][1024][64]
  unsigned short* o_ws = (unsigned short*)(ws + 60817408);   // 134 MB [8192][8192]

  transpose_cvt_kernel<<<dim3(64, 16), 256, 0, stream>>>(W1, w1t, 512, 2048);
  transpose_cvt_kernel<<<dim3(16, 256), 256, 0, stream>>>(W2, w2t, 8192, 512);
  transpose_cvt_kernel<<<dim3(16, 256), 256, 0, stream>>>(v, vt, 8192, 512);
  cvt_bf16_kernel<<<4096, 256, 0, stream>>>(v, vbf, 1048576);
  gemm1_kernel<<<dim3(16, 64), 256, 0, stream>>>(vbf, w1t, b1, q_ws, k_ws);
  attn_kernel<<<dim3(32, 16, 8), 512, 0, stream>>>(q_ws, k_ws, vt, pad, attn, o_ws);
  gemm2_kernel<<<dim3(4, 128), 256, 0, stream>>>(o_ws, w2t, b2, out);
}